// Round 2
// baseline (236.410 us; speedup 1.0000x reference)
//
#include <hip/hip_runtime.h>

#define EPS_F 1e-5f

// Output layout (floats):
//   [0, 2700)                : ref3d  (1,900,3)  = reference_points copy
//   [2700, 2700+5529600)     : sampled_feats (1,256,900,6,1,4)
//                              idx = 2700 + c*21600 + q*24 + n*4 + l
//   [5532300, 5537700)       : mask (1,1,900,6,1,1), idx = 5532300 + q*6 + n
//
// Grid: 5400 blocks = (q,n) pairs; 256 threads = channel c.
// Projection is block-uniform. One uniform umbrella branch (coarsest level's
// valid window is a superset of all finer ones); inside, all 16 corner loads
// are issued unconditionally (clamped addresses, masked weights) so the
// compiler can batch them -> high memory-level parallelism on scattered loads.
__global__ __launch_bounds__(256) void fs_kernel(
    const float* __restrict__ f0, const float* __restrict__ f1,
    const float* __restrict__ f2, const float* __restrict__ f3,
    const float* __restrict__ ref_pts, const float* __restrict__ pc_range,
    const float* __restrict__ img_shape, const float* __restrict__ l2i,
    float* __restrict__ out)
{
    const int bid = blockIdx.x;
    const int n = bid % 6;          // camera
    const int q = bid / 6;          // query
    const int c = threadIdx.x;      // channel

    // ---- projection (uniform across block) ----
    const float X = ref_pts[q * 3 + 0] * (pc_range[3] - pc_range[0]) + pc_range[0];
    const float Y = ref_pts[q * 3 + 1] * (pc_range[4] - pc_range[1]) + pc_range[1];
    const float Z = ref_pts[q * 3 + 2] * (pc_range[5] - pc_range[2]) + pc_range[2];
    const float* M = l2i + n * 16;
    const float cx = M[0] * X + M[1] * Y + M[2]  * Z + M[3];
    const float cy = M[4] * X + M[5] * Y + M[6]  * Z + M[7];
    const float cz = M[8] * X + M[9] * Y + M[10] * Z + M[11];
    const float denom = fmaxf(cz, EPS_F);
    const float u = (cx / denom) / img_shape[1];   // x / 1600
    const float v = (cy / denom) / img_shape[0];   // y / 928
    const float xn = (u - 0.5f) * 2.0f;
    const float yn = (v - 0.5f) * 2.0f;

    // ---- mask output (one lane) ----
    if (threadIdx.x == 0) {
        const bool m = (cz > EPS_F) && (xn > -1.0f) && (xn < 1.0f)
                                    && (yn > -1.0f) && (yn < 1.0f);
        out[5532300 + q * 6 + n] = m ? 1.0f : 0.0f;
    }
    // ---- ref3d copy (3 lanes of the n==0 block for this q) ----
    if (n == 0 && threadIdx.x < 3) {
        out[q * 3 + threadIdx.x] = ref_pts[q * 3 + threadIdx.x];
    }

    // ---- umbrella validity: coarsest level (W=25,H=15) has the widest
    //      valid window xn in (-1-1/W, 1+1/W); NaN/Inf compare false ----
    const float ix3 = ((xn + 1.0f) * 25.0f - 1.0f) * 0.5f;
    const float iy3 = ((yn + 1.0f) * 15.0f - 1.0f) * 0.5f;
    const float ix3f = floorf(ix3);
    const float iy3f = floorf(iy3);
    const bool any_valid = (ix3f >= -1.0f) && (ix3f <= 24.0f)
                        && (iy3f >= -1.0f) && (iy3f <= 14.0f);

    float acc[4] = {0.0f, 0.0f, 0.0f, 0.0f};

    if (any_valid) {   // block-uniform branch
        const float* const feats[4] = {f0, f1, f2, f3};
        const int Hs[4] = {116, 58, 29, 15};
        const int Ws[4] = {200, 100, 50, 25};

        #pragma unroll
        for (int l = 0; l < 4; ++l) {
            const int W = Ws[l];
            const int H = Hs[l];
            const float ix = ((xn + 1.0f) * (float)W - 1.0f) * 0.5f;
            const float iy = ((yn + 1.0f) * (float)H - 1.0f) * 0.5f;
            const float ix0f = floorf(ix);
            const float iy0f = floorf(iy);
            const float wx1 = ix - ix0f, wy1 = iy - iy0f;
            const bool vx0 = (ix0f >= 0.0f)  && (ix0f <= (float)(W - 1));
            const bool vx1 = (ix0f >= -1.0f) && (ix0f <= (float)(W - 2));
            const bool vy0 = (iy0f >= 0.0f)  && (iy0f <= (float)(H - 1));
            const bool vy1 = (iy0f >= -1.0f) && (iy0f <= (float)(H - 2));

            // under umbrella, |xn|,|yn| <= ~1.07 -> small ints, no overflow
            const int x0 = (int)ix0f;
            const int y0 = (int)iy0f;
            const int x0c = min(max(x0, 0), W - 1);
            const int x1c = min(max(x0 + 1, 0), W - 1);
            const int y0c = min(max(y0, 0), H - 1);
            const int y1c = min(max(y0 + 1, 0), H - 1);

            const float* base = feats[l] + (size_t)(n * 256 + c) * (size_t)(H * W);
            // 4 unconditional scattered loads (clamped, always in-bounds)
            const float v00 = base[y0c * W + x0c];
            const float v01 = base[y0c * W + x1c];
            const float v10 = base[y1c * W + x0c];
            const float v11 = base[y1c * W + x1c];

            const float wx0e = vx0 ? (1.0f - wx1) : 0.0f;
            const float wx1e = vx1 ? wx1 : 0.0f;
            const float wy0e = vy0 ? (1.0f - wy1) : 0.0f;
            const float wy1e = vy1 ? wy1 : 0.0f;

            acc[l] = wy0e * (wx0e * v00 + wx1e * v01)
                   + wy1e * (wx0e * v10 + wx1e * v11);
        }
    }

    // ---- sampled_feats write: 16B contiguous per thread (l innermost) ----
    float4 o;
    o.x = acc[0]; o.y = acc[1]; o.z = acc[2]; o.w = acc[3];
    *(float4*)(out + 2700 + (size_t)c * 21600 + q * 24 + n * 4) = o;
}

extern "C" void kernel_launch(void* const* d_in, const int* in_sizes, int n_in,
                              void* d_out, int out_size, void* d_ws, size_t ws_size,
                              hipStream_t stream) {
    const float* f0  = (const float*)d_in[0];  // (1,6,256,116,200)
    const float* f1  = (const float*)d_in[1];  // (1,6,256,58,100)
    const float* f2  = (const float*)d_in[2];  // (1,6,256,29,50)
    const float* f3  = (const float*)d_in[3];  // (1,6,256,15,25)
    const float* rp  = (const float*)d_in[4];  // (1,900,3)
    const float* pcr = (const float*)d_in[5];  // (6,)
    const float* ish = (const float*)d_in[6];  // (2,)
    const float* l2i = (const float*)d_in[7];  // (1,6,4,4)
    float* out = (float*)d_out;

    fs_kernel<<<5400, 256, 0, stream>>>(f0, f1, f2, f3, rp, pcr, ish, l2i, out);
}